// Round 3
// baseline (261.676 us; speedup 1.0000x reference)
//
#include <hip/hip_runtime.h>

// Problem constants (match reference setup_inputs).
constexpr int Bc = 4;
constexpr int Nc = 2048;
constexpr int Dc = 3;
constexpr int Sc = 8;

typedef float f32x4 __attribute__((ext_vector_type(4)));

// y[b,s,i,j] = exp(-(sum_d |x[b,i,d]-x[b,j,d]|)^2 / (2*sigma_s^2))
// One block -> one (b,i) row. One thread -> 8 consecutive j, all 8 sigmas.
// Stores are nontemporal: output is write-once/never-read, bypass L2 allocation.
__global__ __launch_bounds__(256) void gauss_l1_kernel(
    const float* __restrict__ x,       // [B, N, D=3]
    const float* __restrict__ sigmas,  // [S=8]
    float* __restrict__ out)           // [B, S, N, N]
{
    const int b = blockIdx.y;
    const int i = blockIdx.x;
    const int j0 = threadIdx.x * 8;

    // x[b,i,:] — uniform across the block (scalar loads).
    const float* xi = x + ((size_t)b * Nc + i) * Dc;
    const float xi0 = xi[0], xi1 = xi[1], xi2 = xi[2];

    // x[b,j0..j0+7,:] — 24 consecutive floats, 96B-aligned -> 6 f32x4 loads.
    float f[24];
    const f32x4* xj4 = reinterpret_cast<const f32x4*>(x + ((size_t)b * Nc + j0) * Dc);
    #pragma unroll
    for (int q = 0; q < 6; ++q) {
        const f32x4 t = xj4[q];
        f[q * 4 + 0] = t.x; f[q * 4 + 1] = t.y;
        f[q * 4 + 2] = t.z; f[q * 4 + 3] = t.w;
    }

    // Squared L1 distances for 8 j's (all indices compile-time -> registers).
    float d2[8];
    #pragma unroll
    for (int k = 0; k < 8; ++k) {
        const float d = fabsf(xi0 - f[k * 3 + 0])
                      + fabsf(xi1 - f[k * 3 + 1])
                      + fabsf(xi2 - f[k * 3 + 2]);
        d2[k] = d * d;
    }

    // -1/(2*sigma^2) — uniform scalar loads.
    float inv[Sc];
    #pragma unroll
    for (int s = 0; s < Sc; ++s) {
        const float sg = sigmas[s];
        inv[s] = -1.0f / (2.0f * sg * sg);
    }

    const size_t row = ((size_t)b * Sc * Nc + i) * Nc + j0;  // s=0 offset
    #pragma unroll
    for (int s = 0; s < Sc; ++s) {
        f32x4 v0, v1;
        v0.x = __expf(d2[0] * inv[s]);
        v0.y = __expf(d2[1] * inv[s]);
        v0.z = __expf(d2[2] * inv[s]);
        v0.w = __expf(d2[3] * inv[s]);
        v1.x = __expf(d2[4] * inv[s]);
        v1.y = __expf(d2[5] * inv[s]);
        v1.z = __expf(d2[6] * inv[s]);
        v1.w = __expf(d2[7] * inv[s]);
        f32x4* p = reinterpret_cast<f32x4*>(out + row + (size_t)s * Nc * Nc);
        __builtin_nontemporal_store(v0, p);
        __builtin_nontemporal_store(v1, p + 1);
    }
}

extern "C" void kernel_launch(void* const* d_in, const int* in_sizes, int n_in,
                              void* d_out, int out_size, void* d_ws, size_t ws_size,
                              hipStream_t stream) {
    const float* x = (const float*)d_in[0];        // [B, N, 3] fp32
    const float* sigmas = (const float*)d_in[1];   // [8] fp32
    float* out = (float*)d_out;                    // [B, S, N, N] fp32

    dim3 block(256, 1, 1);
    dim3 grid(Nc, Bc, 1);                          // one block per (i, b) row
    gauss_l1_kernel<<<grid, block, 0, stream>>>(x, sigmas, out);
}

// Round 4
// 131.780 us; speedup vs baseline: 1.9857x; 1.9857x over previous
//
#include <hip/hip_runtime.h>

// Problem constants (match reference setup_inputs).
constexpr int Bc = 4;
constexpr int Nc = 2048;
constexpr int Dc = 3;
constexpr int Sc = 8;

typedef float f32x4 __attribute__((ext_vector_type(4)));

// y[b,s,i,j] = exp(-(sum_d |x[b,i,d]-x[b,j,d]|)^2 / (2*sigma_s^2))
// One thread -> one (b,i) row, 4 consecutive j, all 8 sigmas.
// Every store instruction is wave-contiguous (64 lanes x 16B = 1KB) and
// nontemporal (output is write-once/never-read -> bypass L2 allocation).
__global__ __launch_bounds__(256) void gauss_l1_kernel(
    const float* __restrict__ x,       // [B, N, D=3]
    const float* __restrict__ sigmas,  // [S=8]
    float* __restrict__ out)           // [B, S, N, N]
{
    const int b = blockIdx.z;
    const int i = blockIdx.y;
    const int j0 = (blockIdx.x * blockDim.x + threadIdx.x) * 4;

    // x[b,i,:] — uniform across the block (scalar loads).
    const float* xi = x + ((size_t)b * Nc + i) * Dc;
    const float xi0 = xi[0], xi1 = xi[1], xi2 = xi[2];

    // x[b,j0..j0+3,:] — 12 consecutive floats -> 3 f32x4 loads.
    const f32x4* xj4 = reinterpret_cast<const f32x4*>(x + ((size_t)b * Nc + j0) * Dc);
    const f32x4 p0 = xj4[0];  // j0:{x,y,z}, j1:{x}
    const f32x4 p1 = xj4[1];  // j1:{y,z},   j2:{x,y}
    const f32x4 p2 = xj4[2];  // j2:{z},     j3:{x,y,z}

    float d2[4];
    {
        float d;
        d = fabsf(xi0 - p0.x) + fabsf(xi1 - p0.y) + fabsf(xi2 - p0.z); d2[0] = d * d;
        d = fabsf(xi0 - p0.w) + fabsf(xi1 - p1.x) + fabsf(xi2 - p1.y); d2[1] = d * d;
        d = fabsf(xi0 - p1.z) + fabsf(xi1 - p1.w) + fabsf(xi2 - p2.x); d2[2] = d * d;
        d = fabsf(xi0 - p2.y) + fabsf(xi1 - p2.z) + fabsf(xi2 - p2.w); d2[3] = d * d;
    }

    // -1/(2*sigma^2) — uniform scalar loads.
    float inv[Sc];
    #pragma unroll
    for (int s = 0; s < Sc; ++s) {
        const float sg = sigmas[s];
        inv[s] = -1.0f / (2.0f * sg * sg);
    }

    const size_t row = ((size_t)b * Sc * Nc + i) * Nc + j0;  // s=0 offset
    #pragma unroll
    for (int s = 0; s < Sc; ++s) {
        f32x4 v;
        v.x = __expf(d2[0] * inv[s]);
        v.y = __expf(d2[1] * inv[s]);
        v.z = __expf(d2[2] * inv[s]);
        v.w = __expf(d2[3] * inv[s]);
        __builtin_nontemporal_store(
            v, reinterpret_cast<f32x4*>(out + row + (size_t)s * Nc * Nc));
    }
}

extern "C" void kernel_launch(void* const* d_in, const int* in_sizes, int n_in,
                              void* d_out, int out_size, void* d_ws, size_t ws_size,
                              hipStream_t stream) {
    const float* x = (const float*)d_in[0];        // [B, N, 3] fp32
    const float* sigmas = (const float*)d_in[1];   // [8] fp32
    float* out = (float*)d_out;                    // [B, S, N, N] fp32

    dim3 block(256, 1, 1);
    dim3 grid(Nc / (256 * 4), Nc, Bc);             // (2, 2048, 4)
    gauss_l1_kernel<<<grid, block, 0, stream>>>(x, sigmas, out);
}

// Round 5
// 85.279 us; speedup vs baseline: 3.0685x; 1.5453x over previous
//
#include <hip/hip_runtime.h>

// Problem constants (match reference setup_inputs).
constexpr int Bc = 4;
constexpr int Nc = 2048;
constexpr int Dc = 3;
constexpr int Sc = 8;

typedef float f32x4 __attribute__((ext_vector_type(4)));

// y[b,s,i,j] = exp(-(sum_d |x[b,i,d]-x[b,j,d]|)^2 / (2*sigma_s^2))
// One block -> one (plane, i) row-segment, where plane = b*S + s = blockIdx.z.
// Each thread: 4 consecutive j, ONE sigma, one wave-contiguous NT store.
// blockIdx.z is the slowest dispatch dim -> concurrent blocks write within
// 1-2 consecutive 16MB planes: dense chip-wide write front (fill-like),
// instead of 8 interleaved 16MB-strided streams (DRAM row thrash).
__global__ __launch_bounds__(256) void gauss_l1_kernel(
    const float* __restrict__ x,       // [B, N, D=3]
    const float* __restrict__ sigmas,  // [S=8]
    float* __restrict__ out)           // [B, S, N, N]
{
    const int plane = blockIdx.z;          // 0..31 == b*Sc + s
    const int b = plane >> 3;              // Sc == 8
    const int s = plane & 7;
    const int i = blockIdx.y;
    const int j0 = (blockIdx.x * blockDim.x + threadIdx.x) * 4;

    // x[b,i,:] — uniform across the block (scalar loads).
    const float* xi = x + ((size_t)b * Nc + i) * Dc;
    const float xi0 = xi[0], xi1 = xi[1], xi2 = xi[2];

    // x[b,j0..j0+3,:] — 12 consecutive floats -> 3 f32x4 loads (L2-resident).
    const f32x4* xj4 = reinterpret_cast<const f32x4*>(x + ((size_t)b * Nc + j0) * Dc);
    const f32x4 p0 = xj4[0];  // j0:{x,y,z}, j1:{x}
    const f32x4 p1 = xj4[1];  // j1:{y,z},   j2:{x,y}
    const f32x4 p2 = xj4[2];  // j2:{z},     j3:{x,y,z}

    float d2[4];
    {
        float d;
        d = fabsf(xi0 - p0.x) + fabsf(xi1 - p0.y) + fabsf(xi2 - p0.z); d2[0] = d * d;
        d = fabsf(xi0 - p0.w) + fabsf(xi1 - p1.x) + fabsf(xi2 - p1.y); d2[1] = d * d;
        d = fabsf(xi0 - p1.z) + fabsf(xi1 - p1.w) + fabsf(xi2 - p2.x); d2[2] = d * d;
        d = fabsf(xi0 - p2.y) + fabsf(xi1 - p2.z) + fabsf(xi2 - p2.w); d2[3] = d * d;
    }

    // -1/(2*sigma^2) for this block's single sigma (uniform scalar).
    const float sg = sigmas[s];
    const float inv = -1.0f / (2.0f * sg * sg);

    f32x4 v;
    v.x = __expf(d2[0] * inv);
    v.y = __expf(d2[1] * inv);
    v.z = __expf(d2[2] * inv);
    v.w = __expf(d2[3] * inv);

    const size_t off = ((size_t)plane * Nc + i) * Nc + j0;
    __builtin_nontemporal_store(v, reinterpret_cast<f32x4*>(out + off));
}

extern "C" void kernel_launch(void* const* d_in, const int* in_sizes, int n_in,
                              void* d_out, int out_size, void* d_ws, size_t ws_size,
                              hipStream_t stream) {
    const float* x = (const float*)d_in[0];        // [B, N, 3] fp32
    const float* sigmas = (const float*)d_in[1];   // [8] fp32
    float* out = (float*)d_out;                    // [B, S, N, N] fp32

    dim3 block(256, 1, 1);
    dim3 grid(Nc / (256 * 4), Nc, Bc * Sc);        // (2, 2048, 32)
    gauss_l1_kernel<<<grid, block, 0, stream>>>(x, sigmas, out);
}